// Round 3
// baseline (1932.502 us; speedup 1.0000x reference)
//
#include <hip/hip_runtime.h>
#include <hip/hip_fp16.h>
#include <stdint.h>

// sLSTM cell, T=512, B=16, H=4 heads, D=256, G=4 gates. fp32 in/out.
//
// R3 design (MFMA, batch-amortized weights):
//  - 16 active blocks = (head, j-quarter jq). Block computes, per step,
//    Y[16 batches x 256 outdims] = H[16 x 256] @ W[256 x 256] with
//    mfma_f32_16x16x32_f16 (M=16 == batch). Wave w == gate g; wave owns
//    4 N-tiles (64 dims) x 8 K-steps = 32 B-frags = 128 VGPRs, loaded once
//    and PINNED with asm barriers (R2's compiler rematerialized them ->
//    128 KB/CU/step of L2 traffic; that was the bottleneck).
//  - h exchange is intra-head: 4 sibling blocks on one XCD (bid&7 = head
//    under round-robin placement). Same proven protocol: agent-scope
//    relaxed u32, hi16 = f16(h), lo16 = step tag, 2-slot ping-pong.
//  - Per step: spin+fill h_lds -> B1 -> MFMA -> raw_lds -> B2 -> gates
//    (thread owns 4 (batch,dim) state items) -> publish + own h_lds write.
//  - Grid 32 (bid&7 in [4,8) exit immediately): keeps head's 4 blocks on
//    one XCD. ws: 2 MB packed f16 weights + 128 KB exchange.

#define NTS 512
#define OUTS_ELEMS (NTS * 16 * 1024)   // 8388608 floats of `outs`

typedef _Float16 v8h __attribute__((ext_vector_type(8)));
typedef float v4f __attribute__((ext_vector_type(4)));

union F16x8 { uint32_t u[4]; v8h h; };

// Packed blob, u32 index: ((((head*4+jq)*4+g)*4+nt)*8+kk)*64*4 + lane*4 + c
// B-frag element j in [0,8): din = kk*32 + (lane>>4)*8 + 2c+e (j = 2c+e),
// dout = jq*64 + nt*16 + (lane&15).
// Weff[h,g,dout,din] = rk[h, (din%64)*4+g, dout/64, (dout%64)*4+din/64]
// (validated in R1/R2).
__global__ void repack_weights(const float* __restrict__ rk,
                               uint32_t* __restrict__ wp) {
  int tid = blockIdx.x * 256 + threadIdx.x;      // [0, 524288)
  int c    = tid & 3;
  int lane = (tid >> 2) & 63;
  int kk   = (tid >> 8) & 7;
  int nt   = (tid >> 11) & 3;
  int g    = (tid >> 13) & 3;
  int jq   = (tid >> 15) & 3;
  int head = tid >> 17;
  int dout = jq * 64 + nt * 16 + (lane & 15);
  uint32_t word = 0;
  #pragma unroll
  for (int e = 0; e < 2; ++e) {
    int din = kk * 32 + (lane >> 4) * 8 + c * 2 + e;
    float v = rk[head * 262144 + ((din & 63) * 4 + g) * 1024 + jq * 256 +
                 (dout & 63) * 4 + (din >> 6)];
    word |= (uint32_t)__half_as_ushort(__float2half(v)) << (16 * e);
  }
  wp[tid] = word;
}

__global__ __launch_bounds__(256, 1) void slstm_main(
    const float* __restrict__ x, const float* __restrict__ bias,
    const uint32_t* __restrict__ wp, uint32_t* hex,
    float* __restrict__ out) {
  const int bid = blockIdx.x;
  const int head = bid & 7;        // bid%8 -> XCD: siblings co-located
  const int jq = bid >> 3;
  if (head >= 4) return;           // 16 idle blocks exit (no barriers yet)

  const int lane = threadIdx.x & 63;
  const int w = threadIdx.x >> 6;  // wave == gate
  const int m15 = lane & 15, quad = lane >> 4;

  // h_lds[m][k]: f16 bits of h_{t-1}; row stride 264 (16B-aligned, padded).
  // raw_lds[g][m][dl]: MFMA outputs (Ry) for gate combine; stride 66 pads.
  __shared__ __align__(16) unsigned short h_lds[16][264];
  __shared__ float raw_lds[4][16][66];

  // ---- B fragments: 32 frags x 4 u32 = 128 VGPRs, pinned ----
  uint32_t bw[128];
  {
    const uint4* wp4 = (const uint4*)wp;
    #pragma unroll
    for (int nt = 0; nt < 4; ++nt)
      #pragma unroll
      for (int kk = 0; kk < 8; ++kk) {
        uint4 v = wp4[((((head * 4 + jq) * 4 + w) * 4 + nt) * 8 + kk) * 64 + lane];
        int i = (nt * 8 + kk) * 4;
        bw[i] = v.x; bw[i + 1] = v.y; bw[i + 2] = v.z; bw[i + 3] = v.w;
      }
    #pragma unroll
    for (int i = 0; i < 128; ++i) asm volatile("" : "+v"(bw[i]));
  }

  const int xcol = head * 256 + jq * 64 + lane;   // d-column in the 1024
  float bg[4];
  #pragma unroll
  for (int g = 0; g < 4; ++g) bg[g] = bias[g * 1024 + xcol];

  float xv[16];
  #pragma unroll
  for (int r = 0; r < 4; ++r)
    #pragma unroll
    for (int g = 0; g < 4; ++g)
      xv[r * 4 + g] = x[(w * 4 + r) * 4096 + g * 1024 + xcol];

  float hs[4] = {0.f, 0.f, 0.f, 0.f}, cs[4] = {0.f, 0.f, 0.f, 0.f};
  float nns[4] = {0.f, 0.f, 0.f, 0.f}, msx[4] = {0.f, 0.f, 0.f, 0.f};

  #pragma unroll 1
  for (int t = 0; t < NTS; ++t) {
    // ---- spin: acquire siblings' h(t-1) quarters, fill h_lds ----
    if (t > 0) {
      const uint32_t tg = (uint32_t)(t - 1);
      uint32_t* base = hex + ((t - 1) & 1) * 16384 + head * 4096;
      uint32_t vv[4][4];
      bool ok; int spins = 0;
      do {
        ok = true;
        #pragma unroll
        for (int s = 0; s < 4; ++s) {
          if (s == jq) continue;
          #pragma unroll
          for (int r = 0; r < 4; ++r) {
            uint32_t v = __hip_atomic_load(base + (w * 4 + r) * 256 + s * 64 + lane,
                                           __ATOMIC_RELAXED,
                                           __HIP_MEMORY_SCOPE_AGENT);
            vv[s][r] = v;
            ok = ok && ((v & 0xffffu) == tg);
          }
        }
      } while (!__all(ok) && ++spins < (1 << 15));
      #pragma unroll
      for (int s = 0; s < 4; ++s) {
        if (s == jq) continue;
        #pragma unroll
        for (int r = 0; r < 4; ++r)
          h_lds[w * 4 + r][s * 64 + lane] = (unsigned short)(vv[s][r] >> 16);
      }
    }
    __syncthreads();   // B1: h_lds complete (incl. own range from t-1 gates)

    // ---- MFMA: Ry[16 x 64] for this wave's gate ----
    if (t > 0) {
      v4f acc[4];
      #pragma unroll
      for (int nt = 0; nt < 4; ++nt) acc[nt] = (v4f){0.f, 0.f, 0.f, 0.f};
      #pragma unroll
      for (int kk = 0; kk < 8; ++kk) {
        F16x8 af;
        uint4 a4 = *(const uint4*)&h_lds[m15][kk * 32 + quad * 8];
        af.u[0] = a4.x; af.u[1] = a4.y; af.u[2] = a4.z; af.u[3] = a4.w;
        #pragma unroll
        for (int nt = 0; nt < 4; ++nt) {
          F16x8 bf; int i = (nt * 8 + kk) * 4;
          bf.u[0] = bw[i]; bf.u[1] = bw[i + 1];
          bf.u[2] = bw[i + 2]; bf.u[3] = bw[i + 3];
          acc[nt] = __builtin_amdgcn_mfma_f32_16x16x32_f16(af.h, bf.h, acc[nt],
                                                           0, 0, 0);
        }
      }
      // D layout: m = quad*4 + r, n = lane&15  ->  raw_lds[gate][m][dl]
      #pragma unroll
      for (int nt = 0; nt < 4; ++nt)
        #pragma unroll
        for (int r = 0; r < 4; ++r)
          raw_lds[w][quad * 4 + r][nt * 16 + m15] = acc[nt][r];
    }
    __syncthreads();   // B2: raw_lds complete, mfma reads of h_lds done

    // ---- prefetch x(t+1); gate/state update for 4 (m,dl) items ----
    float xn[16];
    if (t < NTS - 1) {
      #pragma unroll
      for (int r = 0; r < 4; ++r)
        #pragma unroll
        for (int g = 0; g < 4; ++g)
          xn[r * 4 + g] = x[(t + 1) * 65536 + (w * 4 + r) * 4096 + g * 1024 + xcol];
    }
    #pragma unroll
    for (int r = 0; r < 4; ++r) {
      float a0 = 0.f, a1 = 0.f, a2 = 0.f, a3 = 0.f;
      if (t > 0) {
        a0 = raw_lds[0][w * 4 + r][lane];
        a1 = raw_lds[1][w * 4 + r][lane];
        a2 = raw_lds[2][w * 4 + r][lane];
        a3 = raw_lds[3][w * 4 + r][lane];
      }
      float ri = a0 + xv[r * 4 + 0] + bg[0];
      float rf = a1 + xv[r * 4 + 1] + bg[1];
      float rz = a2 + xv[r * 4 + 2] + bg[2];
      float ro = a3 + xv[r * 4 + 3] + bg[3];

      float lsf = fminf(rf, 0.f) - __logf(1.f + __expf(-fabsf(rf)));
      float lf = msx[r] + lsf;
      float mnew = (t == 0) ? ri : fmaxf(ri, lf);
      float og = 1.f / (1.f + __expf(-ro));
      float ig = __expf(ri - mnew);
      float fg = __expf(lf - mnew);
      float ez = __expf(2.f * rz);
      float th = 1.f - 2.f / (ez + 1.f);          // tanh(rz)
      float cnew = fg * cs[r] + ig * th;
      float nnew = fg * hs[r] + ig;               // reference uses h here
      float hnew = og * cnew / nnew;
      hs[r] = hnew; cs[r] = cnew; nns[r] = nnew; msx[r] = mnew;

      out[t * 16384 + (w * 4 + r) * 1024 + xcol] = hnew;
      unsigned short hf = __half_as_ushort(__float2half(hnew));
      h_lds[w * 4 + r][jq * 64 + lane] = hf;      // own quarter for t+1
      __hip_atomic_store(hex + (t & 1) * 16384 + head * 4096 +
                             (w * 4 + r) * 256 + jq * 64 + lane,
                         ((uint32_t)hf << 16) | (uint32_t)t,
                         __ATOMIC_RELAXED, __HIP_MEMORY_SCOPE_AGENT);
    }
    if (t < NTS - 1) {
      #pragma unroll
      for (int i = 0; i < 16; ++i) xv[i] = xn[i];
    }
  }

  // ---- final_state: stack (h, c, n, m) ----
  float* fs = out + OUTS_ELEMS;
  #pragma unroll
  for (int r = 0; r < 4; ++r) {
    int o = (w * 4 + r) * 1024 + xcol;
    fs[o] = hs[r];
    fs[16384 + o] = cs[r];
    fs[32768 + o] = nns[r];
    fs[49152 + o] = msx[r];
  }
}

extern "C" void kernel_launch(void* const* d_in, const int* in_sizes, int n_in,
                              void* d_out, int out_size, void* d_ws,
                              size_t ws_size, hipStream_t stream) {
  const float* x    = (const float*)d_in[0];  // (512,16,4096)
  const float* rk   = (const float*)d_in[1];  // (4,256,4,256)
  const float* bias = (const float*)d_in[2];  // (4,4,256)
  uint32_t* wp  = (uint32_t*)d_ws;                         // 2 MB packed f16
  uint32_t* hex = (uint32_t*)((char*)d_ws + (1u << 21));   // 128 KB exchange
  float* out = (float*)d_out;

  repack_weights<<<2048, 256, 0, stream>>>(rk, wp);
  slstm_main<<<32, 256, 0, stream>>>(x, bias, wp, hex, out);
}

// Round 4
// 1560.577 us; speedup vs baseline: 1.2383x; 1.2383x over previous
//
#include <hip/hip_runtime.h>
#include <hip/hip_fp16.h>
#include <stdint.h>

// sLSTM cell, T=512, B=16, H=4 heads, D=256, G=4 gates. fp32 in/out.
//
// R4 design (MFMA batch-amortized, 32 blocks, 64 weight-VGPRs/thread):
//  - R3 post-mortem: 128 weight VGPRs/thread spilled (VGPR_Count=128) ->
//    scratch re-stream every step, latency-bound at 3.46 us/step. Halve the
//    slice: 32 blocks = (head, 8 slices of 32 out-dims x 4 gates). Wave =
//    gate; wave holds 2 N-tiles x 8 K-frags = 64 u32 of f16 weights, pinned.
//  - Per step: Y[16 batches x 32 dims] per gate via mfma_f32_16x16x32_f16
//    (M=16 == batch), A = h[16x256] from LDS, B = register weights.
//  - h exchange: same proven agent-scope relaxed u32 protocol (hi16 =
//    f16(h), lo16 = step tag, 2-slot ping-pong). Each thread spins on 16
//    words (one d-column x 16 batches); safety by B1 barrier (all threads
//    pass spin before any publishes next step).
//  - Gate phase: thread owns 2 (batch m, dim dl) states; x(t+1) prefetch
//    issued right after B2 so it drains during gate VALU, not inside the
//    next spin's vmcnt(0).
//  - ws: 2 MB packed f16 weights + 128 KB exchange.

#define NTS 512
#define OUTS_ELEMS (NTS * 16 * 1024)   // 8388608 floats of `outs`

typedef _Float16 v8h __attribute__((ext_vector_type(8)));
typedef float v4f __attribute__((ext_vector_type(4)));

union F16x8 { uint32_t u[4]; v8h h; };

// Packed blob, u32 index:
//   ((((head*8+s)*4+g)*2+nt)*8+kk)*256 + lane*4 + c
// B-frag element e in {0,1}: din = kk*32 + (lane>>4)*8 + c*2 + e,
// dout(head-local) = s*32 + nt*16 + (lane&15).
// Weff[h,g,dout,din] = rk[h, (din%64)*4+g, dout/64, (dout%64)*4+din/64]
// (mapping validated R1-R3).
__global__ void repack_weights(const float* __restrict__ rk,
                               uint32_t* __restrict__ wp) {
  int tid = blockIdx.x * 256 + threadIdx.x;      // [0, 524288)
  int c    = tid & 3;
  int lane = (tid >> 2) & 63;
  int kk   = (tid >> 8) & 7;
  int nt   = (tid >> 11) & 1;
  int g    = (tid >> 12) & 3;
  int s    = (tid >> 14) & 7;
  int head = tid >> 17;
  int dout = s * 32 + nt * 16 + (lane & 15);
  uint32_t word = 0;
  #pragma unroll
  for (int e = 0; e < 2; ++e) {
    int din = kk * 32 + (lane >> 4) * 8 + c * 2 + e;
    float v = rk[head * 262144 + ((din & 63) * 4 + g) * 1024 +
                 (dout >> 6) * 256 + (dout & 63) * 4 + (din >> 6)];
    word |= (uint32_t)__half_as_ushort(__float2half(v)) << (16 * e);
  }
  wp[tid] = word;
}

__global__ __launch_bounds__(256, 1) void slstm_main(
    const float* __restrict__ x, const float* __restrict__ bias,
    const uint32_t* __restrict__ wp, uint32_t* hex,
    float* __restrict__ out) {
  const int bid = blockIdx.x;      // 32 blocks
  const int head = bid >> 3;       // [0,4)
  const int s = bid & 7;           // out-slice [0,8)
  const int lane = threadIdx.x & 63;
  const int w = threadIdx.x >> 6;  // wave == gate for the MFMA phase
  const int m15 = lane & 15, quad = lane >> 4;
  const int tau = w * 64 + lane;   // [0,256): spin d-column (head-local)

  // h_lds[m][k]: f16 bits of h_{t-1}, row padded to 264 (2-way-free b128).
  // raw_lds[g][m][dl]: per-gate MFMA outputs; stride 67 to spread banks.
  __shared__ __align__(16) unsigned short h_lds[16][264];
  __shared__ float raw_lds[4][16][67];

  // ---- B fragments: 2 nt x 8 kk x 4 u32 = 64 VGPRs, pinned ----
  uint32_t bw[64];
  {
    const uint4* wp4 = (const uint4*)wp;
    const int wbase = (((head * 8 + s) * 4 + w) * 2) * 8 * 64 + lane;
    #pragma unroll
    for (int f = 0; f < 16; ++f) {       // f = nt*8 + kk
      uint4 v = wp4[wbase + f * 64];
      bw[f * 4] = v.x; bw[f * 4 + 1] = v.y;
      bw[f * 4 + 2] = v.z; bw[f * 4 + 3] = v.w;
    }
    #pragma unroll
    for (int i = 0; i < 64; ++i) asm volatile("" : "+v"(bw[i]));
  }

  // ---- state ownership: m_st = w*4+quad, dl(j) = j*16+m15 ----
  const int m_st = w * 4 + quad;
  const int colbase = head * 256 + s * 32;   // column in the 1024

  float bg[8];
  #pragma unroll
  for (int j = 0; j < 2; ++j)
    #pragma unroll
    for (int g = 0; g < 4; ++g)
      bg[j * 4 + g] = bias[g * 1024 + colbase + j * 16 + m15];

  float xv[8];
  #pragma unroll
  for (int j = 0; j < 2; ++j)
    #pragma unroll
    for (int g = 0; g < 4; ++g)
      xv[j * 4 + g] = x[m_st * 4096 + g * 1024 + colbase + j * 16 + m15];

  // zero h_lds (t=0 MFMA then yields 0, matching h0 = 0)
  #pragma unroll
  for (int m = 0; m < 16; ++m) h_lds[m][tau] = 0;

  float hs[2] = {0.f, 0.f}, cs[2] = {0.f, 0.f};
  float nns[2] = {0.f, 0.f}, msx[2] = {0.f, 0.f};

  __syncthreads();

  #pragma unroll 1
  for (int t = 0; t < NTS; ++t) {
    // ---- spin: acquire full h(t-1)[16 x 256] of this head ----
    if (t > 0) {
      const uint32_t tg = (uint32_t)(t - 1);
      uint32_t* base = hex + ((t - 1) & 1) * 16384 + head * 4096 + tau;
      uint32_t vv[16];
      int spins = 0;
      for (;;) {
        bool ok = true;
        #pragma unroll
        for (int m = 0; m < 16; ++m) {
          vv[m] = __hip_atomic_load(base + m * 256, __ATOMIC_RELAXED,
                                    __HIP_MEMORY_SCOPE_AGENT);
          ok = ok && ((vv[m] & 0xffffu) == tg);
        }
        if (__all(ok) || ++spins > (1 << 15)) break;
      }
      #pragma unroll
      for (int m = 0; m < 16; ++m)
        h_lds[m][tau] = (unsigned short)(vv[m] >> 16);
    }
    __syncthreads();   // B1: h_lds complete; all threads passed spin

    // ---- MFMA: Ry[16 x 32] for this wave's gate ----
    {
      v4f acc0 = (v4f){0.f, 0.f, 0.f, 0.f};
      v4f acc1 = (v4f){0.f, 0.f, 0.f, 0.f};
      #pragma unroll
      for (int kk = 0; kk < 8; ++kk) {
        F16x8 af;
        uint4 a4 = *(const uint4*)&h_lds[m15][kk * 32 + quad * 8];
        af.u[0] = a4.x; af.u[1] = a4.y; af.u[2] = a4.z; af.u[3] = a4.w;
        F16x8 b0, b1;
        b0.u[0] = bw[kk * 4]; b0.u[1] = bw[kk * 4 + 1];
        b0.u[2] = bw[kk * 4 + 2]; b0.u[3] = bw[kk * 4 + 3];
        b1.u[0] = bw[32 + kk * 4]; b1.u[1] = bw[32 + kk * 4 + 1];
        b1.u[2] = bw[32 + kk * 4 + 2]; b1.u[3] = bw[32 + kk * 4 + 3];
        acc0 = __builtin_amdgcn_mfma_f32_16x16x32_f16(af.h, b0.h, acc0, 0, 0, 0);
        acc1 = __builtin_amdgcn_mfma_f32_16x16x32_f16(af.h, b1.h, acc1, 0, 0, 0);
      }
      // D layout: m = quad*4 + r, n(dl) = nt*16 + m15
      #pragma unroll
      for (int r = 0; r < 4; ++r) {
        raw_lds[w][quad * 4 + r][m15] = acc0[r];
        raw_lds[w][quad * 4 + r][16 + m15] = acc1[r];
      }
    }
    __syncthreads();   // B2: raw_lds complete; h_lds reads done

    // ---- x(t+1) prefetch first: drains during gate VALU ----
    float xn[8];
    if (t < NTS - 1) {
      const float* xp = x + (t + 1) * 65536 + m_st * 4096 + colbase + m15;
      #pragma unroll
      for (int j = 0; j < 2; ++j)
        #pragma unroll
        for (int g = 0; g < 4; ++g)
          xn[j * 4 + g] = xp[g * 1024 + j * 16];
    }

    // ---- gates/state for 2 (m_st, dl) items ----
    #pragma unroll
    for (int j = 0; j < 2; ++j) {
      const int dl = j * 16 + m15;
      float ri = raw_lds[0][m_st][dl] + xv[j * 4 + 0] + bg[j * 4 + 0];
      float rf = raw_lds[1][m_st][dl] + xv[j * 4 + 1] + bg[j * 4 + 1];
      float rz = raw_lds[2][m_st][dl] + xv[j * 4 + 2] + bg[j * 4 + 2];
      float ro = raw_lds[3][m_st][dl] + xv[j * 4 + 3] + bg[j * 4 + 3];

      float lsf = fminf(rf, 0.f) - __logf(1.f + __expf(-fabsf(rf)));
      float lf = msx[j] + lsf;
      float mnew = (t == 0) ? ri : fmaxf(ri, lf);
      float og = 1.f / (1.f + __expf(-ro));
      float ig = __expf(ri - mnew);
      float fg = __expf(lf - mnew);
      float ez = __expf(2.f * rz);
      float th = 1.f - 2.f / (ez + 1.f);          // tanh(rz)
      float cnew = fg * cs[j] + ig * th;
      float nnew = fg * hs[j] + ig;               // reference uses h here
      float hnew = og * cnew / nnew;
      hs[j] = hnew; cs[j] = cnew; nns[j] = nnew; msx[j] = mnew;

      out[t * 16384 + m_st * 1024 + colbase + dl] = hnew;
      unsigned short hf = __half_as_ushort(__float2half(hnew));
      __hip_atomic_store(hex + (t & 1) * 16384 + head * 4096 +
                             m_st * 256 + s * 32 + dl,
                         ((uint32_t)hf << 16) | (uint32_t)t,
                         __ATOMIC_RELAXED, __HIP_MEMORY_SCOPE_AGENT);
    }
    #pragma unroll
    for (int i = 0; i < 8; ++i) xv[i] = xn[i];
  }

  // ---- final_state: stack (h, c, n, m) ----
  float* fs = out + OUTS_ELEMS;
  #pragma unroll
  for (int j = 0; j < 2; ++j) {
    int o = m_st * 1024 + colbase + j * 16 + m15;
    fs[o] = hs[j];
    fs[16384 + o] = cs[j];
    fs[32768 + o] = nns[j];
    fs[49152 + o] = msx[j];
  }
}

extern "C" void kernel_launch(void* const* d_in, const int* in_sizes, int n_in,
                              void* d_out, int out_size, void* d_ws,
                              size_t ws_size, hipStream_t stream) {
  const float* x    = (const float*)d_in[0];  // (512,16,4096)
  const float* rk   = (const float*)d_in[1];  // (4,256,4,256)
  const float* bias = (const float*)d_in[2];  // (4,4,256)
  uint32_t* wp  = (uint32_t*)d_ws;                         // 2 MB packed f16
  uint32_t* hex = (uint32_t*)((char*)d_ws + (1u << 21));   // 128 KB exchange
  float* out = (float*)d_out;

  repack_weights<<<2048, 256, 0, stream>>>(rk, wp);
  slstm_main<<<32, 256, 0, stream>>>(x, bias, wp, hex, out);
}